// Round 10
// baseline (40.223 us; speedup 1.0000x reference)
//
#include <hip/hip_runtime.h>
#include <math.h>

#define BB 32
#define FF 6
#define NN 1024

// ---- DPP wave-64 reductions (VALU-only, no LDS pipe) -----------------------
template <int CTRL, int RMASK>
__device__ __forceinline__ float dpp_f(float v, float old) {
    return __builtin_bit_cast(float,
        __builtin_amdgcn_update_dpp(__builtin_bit_cast(int, old),
                                    __builtin_bit_cast(int, v),
                                    CTRL, RMASK, 0xF, false));
}
__device__ __forceinline__ float wave_min64(float v) {
    const float I = __builtin_inff();
    v = fminf(v, dpp_f<0x111, 0xF>(v, I));   // row_shr:1
    v = fminf(v, dpp_f<0x112, 0xF>(v, I));   // row_shr:2
    v = fminf(v, dpp_f<0x114, 0xF>(v, I));   // row_shr:4
    v = fminf(v, dpp_f<0x118, 0xF>(v, I));   // row_shr:8
    v = fminf(v, dpp_f<0x142, 0xA>(v, I));   // row_bcast:15 -> rows 1,3
    v = fminf(v, dpp_f<0x143, 0xC>(v, I));   // row_bcast:31 -> rows 2,3
    return __builtin_bit_cast(float,
        __builtin_amdgcn_readlane(__builtin_bit_cast(int, v), 63));
}
__device__ __forceinline__ float wave_sum64(float v) {
    v += dpp_f<0x111, 0xF>(v, 0.0f);
    v += dpp_f<0x112, 0xF>(v, 0.0f);
    v += dpp_f<0x114, 0xF>(v, 0.0f);
    v += dpp_f<0x118, 0xF>(v, 0.0f);
    v += dpp_f<0x142, 0xA>(v, 0.0f);
    v += dpp_f<0x143, 0xC>(v, 0.0f);
    return __builtin_bit_cast(float,
        __builtin_amdgcn_readlane(__builtin_bit_cast(int, v), 63));
}

__device__ __forceinline__ float4 pm4(float4 m, float a2) {
    float4 r;
    if (a2 == 2.0f) {            // dataset fast path: alpha == 1 -> pm = m*m
        r.x = m.x * m.x; r.y = m.y * m.y; r.z = m.z * m.z; r.w = m.w * m.w;
    } else {
        r.x = expf(a2 * logf(m.x));
        r.y = expf(a2 * logf(m.y));
        r.z = expf(a2 * logf(m.z));
        r.w = expf(a2 * logf(m.w));
    }
    return r;
}

// ---------------------------------------------------------------------------
// Pass 1: per-block partial min of strict-upper-triangle d_ij.
// 512 blocks: each stages the 28 KB tile ONCE and processes 2 chunks
// (halves staging traffic vs 1024 blocks). Rows per chunk:
// i = chunk + 32*wid + 128*r (kmin-balanced per wave).
// ---------------------------------------------------------------------------
__global__ __launch_bounds__(256) void k_min(const float* __restrict__ emb,
                                             const float* __restrict__ alphap,
                                             float* __restrict__ partial) {
    __shared__ float s_tile[7][NN];
    __shared__ float red[4];
    const int b = blockIdx.x >> 4, sub = blockIdx.x & 15;
    const int tid = threadIdx.x, wid = tid >> 6, lane = tid & 63;
    const float* e = emb + (size_t)b * FF * NN;

    #pragma unroll
    for (int t = 0; t < 6; ++t) {
        const int idx = t * 256 + tid;
        const int f = idx >> 8, j4 = idx & 255;
        ((float4*)&s_tile[f][0])[j4] = ((const float4*)(e + (size_t)f * NN))[j4];
    }
    {
        const float a2 = 2.0f * alphap[0];
        float4 m = *(const float4*)(e + 4 * NN + 4 * tid);
        *(float4*)&s_tile[6][4 * tid] = pm4(m, a2);
    }
    __syncthreads();

    float vmin = 3.4e38f;
    #pragma unroll
    for (int ch = 0; ch < 2; ++ch) {
        const int chunk = sub * 2 + ch;
        #pragma unroll
        for (int g = 0; g < 2; ++g) {
            int ii[4];
            float ei[4][FF], pmi[4];
            #pragma unroll
            for (int rr = 0; rr < 4; ++rr) {
                ii[rr] = chunk + 32 * wid + 128 * (g * 4 + rr);
                #pragma unroll
                for (int f = 0; f < FF; ++f) ei[rr][f] = s_tile[f][ii[rr]];
                pmi[rr] = s_tile[6][ii[rr]];
            }
            #pragma unroll
            for (int k = 0; k < 4; ++k) {
                if (k >= (ii[0] >> 8)) {                // wave-uniform skip
                    float4 q[FF], pk4;
                    #pragma unroll
                    for (int f = 0; f < FF; ++f)
                        q[f] = ((const float4*)&s_tile[f][k * 256])[lane];
                    pk4 = ((const float4*)&s_tile[6][k * 256])[lane];
                    #pragma unroll
                    for (int rr = 0; rr < 4; ++rr) {
                        const int i = ii[rr], km = i >> 8;
                        if (k > km) {
                            #pragma unroll
                            for (int c = 0; c < 4; ++c) {
                                float acc = 0.0f;
                                #pragma unroll
                                for (int f = 0; f < FF; ++f) {
                                    float t = ((const float*)&q[f])[c] - ei[rr][f];
                                    acc = fmaf(t, t, acc);
                                }
                                vmin = fminf(vmin,
                                    acc * fminf(pmi[rr], ((const float*)&pk4)[c]));
                            }
                        } else if (k == km) {
                            #pragma unroll
                            for (int c = 0; c < 4; ++c) {
                                float acc = 0.0f;
                                #pragma unroll
                                for (int f = 0; f < FF; ++f) {
                                    float t = ((const float*)&q[f])[c] - ei[rr][f];
                                    acc = fmaf(t, t, acc);
                                }
                                float dd = acc * fminf(pmi[rr],
                                                       ((const float*)&pk4)[c]);
                                const int j = k * 256 + lane * 4 + c;
                                vmin = (j > i) ? fminf(vmin, dd) : vmin;
                            }
                        }
                    }
                }
            }
        }
    }
    vmin = wave_min64(vmin);
    if (lane == 0) red[wid] = vmin;
    __syncthreads();
    if (tid == 0)
        partial[blockIdx.x] = fminf(fminf(red[0], red[1]), fminf(red[2], red[3]));
}

// ---------------------------------------------------------------------------
// Pass 2: LDS tile + 4-row-group recompute; pm pre-scaled by s2; DPP-reduced
// row softmax; PLAIN float4 stores (A/B vs round 9's nontemporal).
// Diagonal = +inf -> exp2 gives exact 0 (reference: exp(<=-999) == 0).
// ---------------------------------------------------------------------------
__global__ __launch_bounds__(256) void k_soft(const float* __restrict__ emb,
                                              const float* __restrict__ alphap,
                                              const float* __restrict__ betap,
                                              const float* __restrict__ partial,
                                              float* __restrict__ out) {
    __shared__ float s_tile[7][NN];
    __shared__ float s_dmin;
    const int b = blockIdx.x >> 5, chunk = blockIdx.x & 31;
    const int tid = threadIdx.x, wid = tid >> 6, lane = tid & 63;
    const float* e = emb + (size_t)b * FF * NN;

    if (tid < 16) {                                   // 16 partials per batch
        float v = partial[b * 16 + tid];
        #pragma unroll
        for (int o = 8; o >= 1; o >>= 1) v = fminf(v, __shfl_xor(v, o));
        if (tid == 0) s_dmin = v;
    }
    #pragma unroll
    for (int t = 0; t < 6; ++t) {
        const int idx = t * 256 + tid;
        const int f = idx >> 8, j4 = idx & 255;
        ((float4*)&s_tile[f][0])[j4] = ((const float4*)(e + (size_t)f * NN))[j4];
    }
    __syncthreads();
    const float beta = betap[0];
    const float s2 = beta * beta / s_dmin * 1.4426950408889634f;
    {
        const float a2 = 2.0f * alphap[0];
        float4 m = *(const float4*)(e + 4 * NN + 4 * tid);
        float4 r = pm4(m, a2);
        r.x *= s2; r.y *= s2; r.z *= s2; r.w *= s2;   // pre-scale by s2
        *(float4*)&s_tile[6][4 * tid] = r;
    }
    __syncthreads();

    const int kd = chunk >> 3;                        // diagonal chunk
    #pragma unroll
    for (int g = 0; g < 2; ++g) {
        int ii[4];
        float ei[4][FF], pmi[4];
        #pragma unroll
        for (int rr = 0; rr < 4; ++rr) {
            ii[rr] = chunk * 32 + wid * 8 + g * 4 + rr;
            #pragma unroll
            for (int f = 0; f < FF; ++f) ei[rr][f] = s_tile[f][ii[rr]];
            pmi[rr] = s_tile[6][ii[rr]];
        }
        float d[4][16];
        #pragma unroll
        for (int k = 0; k < 4; ++k) {
            float4 q[FF], pk4;
            #pragma unroll
            for (int f = 0; f < FF; ++f)
                q[f] = ((const float4*)&s_tile[f][k * 256])[lane];
            pk4 = ((const float4*)&s_tile[6][k * 256])[lane];
            #pragma unroll
            for (int rr = 0; rr < 4; ++rr) {
                #pragma unroll
                for (int c = 0; c < 4; ++c) {
                    float acc = 0.0f;
                    #pragma unroll
                    for (int f = 0; f < FF; ++f) {
                        float t = ((const float*)&q[f])[c] - ei[rr][f];
                        acc = fmaf(t, t, acc);
                    }
                    d[rr][k * 4 + c] =
                        acc * fminf(pmi[rr], ((const float*)&pk4)[c]);
                }
            }
            if (k == kd) {
                #pragma unroll
                for (int rr = 0; rr < 4; ++rr) {
                    #pragma unroll
                    for (int c = 0; c < 4; ++c)
                        if (k * 256 + lane * 4 + c == ii[rr])
                            d[rr][k * 4 + c] = __builtin_inff();
                }
            }
        }
        #pragma unroll
        for (int rr = 0; rr < 4; ++rr) {
            float rmin = fminf(d[rr][0], d[rr][1]);
            #pragma unroll
            for (int t = 2; t < 16; ++t) rmin = fminf(rmin, d[rr][t]);
            rmin = wave_min64(rmin);

            float sum = 0.0f;
            #pragma unroll
            for (int t = 0; t < 16; ++t) {
                float p = __builtin_amdgcn_exp2f(rmin - d[rr][t]);  // diag -> 0
                d[rr][t] = p;
                sum += p;
            }
            sum = wave_sum64(sum);
            const float inv = 1.0f / sum;

            float* op = out + ((size_t)b * NN + (size_t)ii[rr]) * NN;
            #pragma unroll
            for (int k = 0; k < 4; ++k) {
                float4 w;
                w.x = d[rr][k * 4 + 0] * inv;
                w.y = d[rr][k * 4 + 1] * inv;
                w.z = d[rr][k * 4 + 2] * inv;
                w.w = d[rr][k * 4 + 3] * inv;
                *(float4*)&op[k * 256 + lane * 4] = w;   // plain store (A/B vs NT)
            }
        }
    }
}

extern "C" void kernel_launch(void* const* d_in, const int* in_sizes, int n_in,
                              void* d_out, int out_size, void* d_ws, size_t ws_size,
                              hipStream_t stream) {
    const float* emb   = (const float*)d_in[0];
    const float* alpha = (const float*)d_in[1];
    const float* beta  = (const float*)d_in[2];
    float* out = (float*)d_out;
    float* partial = (float*)d_ws;   // BB*16 floats, fully rewritten every call

    k_min <<<BB * 16, 256, 0, stream>>>(emb, alpha, partial);
    k_soft<<<BB * 32, 256, 0, stream>>>(emb, alpha, beta, partial, out);
}